// Round 2
// baseline (206.792 us; speedup 1.0000x reference)
//
#include <hip/hip_runtime.h>

// Problem constants (from reference setup_inputs):
// B=2, I=63, H=W=320, HID=128, C=14, DOWN=4, h4=w4=80
#define NB 2
#define NI 63
#define BI (NB*NI)          // 126
#define HW 320
#define HWF (HW*HW)         // 102400 pixels per (b,i)
#define H4 80
#define HW4 (H4*H4)         // 6400
#define HID 128
#define IFM_B (HID*HW4)     // 819200 floats per batch

#define OUT_DEPTH 0
#define OUT_CAN   (BI*HWF)            // 12902400
#define OUT_SCALE (2*BI*HWF)          // 25804800
#define OUT_SHIFT (2*BI*HWF + BI)     // 25804926

// Pool-GEMM tiling
#define KB 64               // hw4 positions per block
#define NKB (HW4/KB)        // 100 blocks per batch
#define FPAD 68             // fT/mT padded row stride (floats)
#define PROW 132            // partial row stride per i (129 used)
#define PBLK (64*PROW)      // per-block partial floats (8448)

// clang ext vector types for nontemporal builtins (HIP float4/int4 are
// classes -> rejected by __builtin_nontemporal_*)
typedef int   vint4  __attribute__((ext_vector_type(4)));
typedef float vflt4  __attribute__((ext_vector_type(4)));

// ---------------------------------------------------------------------------
// Kernel P: per (b, k-chunk of 64 hw4):
//   - stage fT[c][k] (128x64 ifm tile) and mT[i][k] (64x64 mask tile) in LDS
//   - GEMM: partial[i][c] = sum_k mT[i][k]*fT[c][k]  (register-tiled 4i x 4c)
//   - msum partial per i  -> partial[i][128]
//   - can_small for these 64 hw: sum_c fT[c][j]*Wc[c] + bc -> can_ws
// Reads ifm exactly once across the grid.
// Geometry: 200 blocks (2*100) x 512 threads. LDS 52.7 KB -> blocks spread
// over ~200 CUs with 2 waves/SIMD (was: 100 blocks, 101 KB LDS, 1 wave/SIMD).
// ---------------------------------------------------------------------------
__global__ __launch_bounds__(512) void pool_gemm_kernel(
    const int* __restrict__ inst, const float* __restrict__ ifm,
    const float* __restrict__ Wc, const float* __restrict__ bc,
    float* __restrict__ can_ws, float* __restrict__ partial) {
  __shared__ float fT[128][FPAD];   // 34.8 KB
  __shared__ float mT[64][FPAD];    // 17.4 KB
  __shared__ float wc_s[128];

  int bid = blockIdx.x;             // 0..199
  int b = bid / NKB, kb = bid % NKB;
  int k0 = kb * KB;                 // base hw4 for this chunk
  int t = threadIdx.x;              // 0..511

  if (t < 128) wc_s[t] = Wc[t];

  // ---- stage fT: 128 c x 64 k floats, coalesced float4 global reads ----
  const float* fbase = ifm + (long)b * IFM_B;
#pragma unroll
  for (int s = 0; s < 4; ++s) {
    int v = s * 512 + t;            // 0..2047 float4 slots
    int c = v >> 4;                 // 16 float4 per row
    int jq = v & 15;
    float4 x = *(const float4*)(fbase + c * HW4 + k0 + jq * 4);
    *(float4*)&fT[c][jq * 4] = x;
  }
  // ---- stage mT: 64 i x 64 k (row 63 zero-padded) ----
#pragma unroll
  for (int s = 0; s < 8; ++s) {
    int v = s * 512 + t;            // 0..4095
    int i = v >> 6;
    int j = v & 63;
    int hw4 = k0 + j;
    int r = hw4 / H4, col = hw4 - r * H4;
    float m = 0.f;
    if (i < NI)
      m = (float)__builtin_nontemporal_load(
          inst + ((long)(b * NI + i)) * HWF + r * 4 * HW + col * 4);
    mT[i][j] = m;
  }
  __syncthreads();

  // ---- register-tiled GEMM: thread (ti,tc) -> i in [4ti,4ti+4), c = tc+32v ----
  int ti = t >> 5, tc = t & 31;     // ti 0..15, tc 0..31
  int i0 = ti * 4;
  float acc[4][4];
#pragma unroll
  for (int u = 0; u < 4; ++u)
#pragma unroll
    for (int v = 0; v < 4; ++v) acc[u][v] = 0.f;

  for (int k = 0; k < KB; k += 4) {
    float4 a[4], bb[4];
#pragma unroll
    for (int u = 0; u < 4; ++u) a[u] = *(const float4*)&mT[i0 + u][k];
#pragma unroll
    for (int v = 0; v < 4; ++v) bb[v] = *(const float4*)&fT[tc + 32 * v][k];
#pragma unroll
    for (int u = 0; u < 4; ++u)
#pragma unroll
      for (int v = 0; v < 4; ++v)
        acc[u][v] += a[u].x * bb[v].x + a[u].y * bb[v].y +
                     a[u].z * bb[v].z + a[u].w * bb[v].w;
  }

  // ---- write partials: c = tc + 32v (lanes contiguous in tc -> coalesced) ----
  float* pb = partial + (long)bid * PBLK;
#pragma unroll
  for (int u = 0; u < 4; ++u)
#pragma unroll
    for (int v = 0; v < 4; ++v)
      pb[(i0 + u) * PROW + tc + 32 * v] = acc[u][v];

  // ---- msum partial per i: threads 0..63 sum their mT row ----
  if (t < 64) {
    float ms = 0.f;
#pragma unroll
    for (int q = 0; q < KB / 4; ++q) {
      float4 m4 = *(const float4*)&mT[t][q * 4];
      ms += m4.x + m4.y + m4.z + m4.w;
    }
    pb[t * PROW + 128] = ms;

    // ---- can_small for these 64 hw: column read of fT (2-way bank = free) ----
    float ca = bc[0];
#pragma unroll 8
    for (int c = 0; c < 128; ++c) ca += fT[c][t] * wc_s[c];
    can_ws[b * HW4 + k0 + t] = ca;
  }
}

// ---------------------------------------------------------------------------
// Kernel F: per (b,i): reduce 100 partials -> pooled[c], msum; then
// scale/shift via labels. 126 blocks x 128 threads.
// ---------------------------------------------------------------------------
__global__ __launch_bounds__(128) void finish_kernel(
    const float* __restrict__ partial, const int* __restrict__ labels,
    const float* __restrict__ W_scale, const float* __restrict__ b_scale,
    const float* __restrict__ W_shift, const float* __restrict__ b_shift,
    float* __restrict__ scale_out, float* __restrict__ shift_out) {
  __shared__ float pooled[128];
  __shared__ float msum_s;

  int bi = blockIdx.x;            // 0..125
  int b = bi / NI, i = bi % NI;
  int t = threadIdx.x;            // 0..127
  int lane = t & 63;

  const float* pb = partial + ((long)b * NKB) * PBLK + i * PROW;

  float acc = 0.f;
#pragma unroll 4
  for (int kb = 0; kb < NKB; ++kb) acc += pb[(long)kb * PBLK + t];
  pooled[t] = acc;

  // msum: wave 0 lanes each grab two chunks' partials, shuffle-reduce
  if (t < 64) {
    float ms = pb[(long)t * PBLK + 128];
    if (t + 64 < NKB) ms += pb[(long)(t + 64) * PBLK + 128];
    for (int off = 32; off; off >>= 1) ms += __shfl_down(ms, off, 64);
    if (t == 0) msum_s = ms;
  }
  __syncthreads();

  if (t < 64) {
    int lab = labels[bi];
    float valid = (lab != 0) ? 1.f : 0.f;
    float inv = 1.f / fmaxf(msum_s, 1.f);
    float p0 = pooled[lane], p1 = pooled[lane + 64];
    const float* ws = W_scale + lab * HID;
    const float* wh = W_shift + lab * HID;
    float sa = p0 * ws[lane] + p1 * ws[lane + 64];
    float sh = p0 * wh[lane] + p1 * wh[lane + 64];
    for (int off = 32; off; off >>= 1) {
      sa += __shfl_down(sa, off, 64);
      sh += __shfl_down(sh, off, 64);
    }
    if (lane == 0) {
      scale_out[bi] = (sa * inv + b_scale[lab]) * valid;
      shift_out[bi] = (sh * inv + b_shift[lab]) * valid;
    }
  }
}

// ---------------------------------------------------------------------------
// Kernel C: full-res outputs. 2048 contiguous pixels per block (50 blocks per
// (b,i) image). Each thread: 2x int4 NT loads, 4x float4 NT stores (8 px).
// Streaming data bypasses L2 via nontemporal hints; can_ws/labels/scale stay
// cached.
// ---------------------------------------------------------------------------
__global__ __launch_bounds__(256) void out_kernel(
    const int* __restrict__ inst, const float* __restrict__ can_ws,
    const int* __restrict__ labels,
    const float* __restrict__ scale_arr, const float* __restrict__ shift_arr,
    float* __restrict__ out_depth, float* __restrict__ out_can) {
  int blk = blockIdx.x;          // 0..6299
  int bi = blk / 50;
  int chunk = blk - bi * 50;
  int b = bi / NI;
  int pix = chunk * 2048 + threadIdx.x * 8;
  int h = pix / HW, w = pix - h * HW;   // all 8 pixels in same row (320%8==0)

  // w is a multiple of 8 -> (w>>2) even -> float2-aligned; covers both w4 cells
  const float2 c2 = *(const float2*)(can_ws + b * HW4 + (h >> 2) * H4 + (w >> 2));
  int lab = labels[bi];
  float valid = (lab != 0) ? 1.f : 0.f;
  float sc = scale_arr[bi];
  float sh = shift_arr[bi];
  float cv0 = c2.x * valid;
  float cv1 = c2.y * valid;

  long base = (long)bi * HWF + pix;
  const vint4 iv0 = __builtin_nontemporal_load((const vint4*)(inst + base));
  const vint4 iv1 = __builtin_nontemporal_load((const vint4*)(inst + base + 4));
  vflt4 cf0, cf1, df0, df1;
  cf0.x = cv0 * (float)iv0.x;
  cf0.y = cv0 * (float)iv0.y;
  cf0.z = cv0 * (float)iv0.z;
  cf0.w = cv0 * (float)iv0.w;
  cf1.x = cv1 * (float)iv1.x;
  cf1.y = cv1 * (float)iv1.y;
  cf1.z = cv1 * (float)iv1.z;
  cf1.w = cv1 * (float)iv1.w;
  df0.x = fmaxf(cf0.x * sc + sh, 0.001f);
  df0.y = fmaxf(cf0.y * sc + sh, 0.001f);
  df0.z = fmaxf(cf0.z * sc + sh, 0.001f);
  df0.w = fmaxf(cf0.w * sc + sh, 0.001f);
  df1.x = fmaxf(cf1.x * sc + sh, 0.001f);
  df1.y = fmaxf(cf1.y * sc + sh, 0.001f);
  df1.z = fmaxf(cf1.z * sc + sh, 0.001f);
  df1.w = fmaxf(cf1.w * sc + sh, 0.001f);
  __builtin_nontemporal_store(cf0, (vflt4*)(out_can + base));
  __builtin_nontemporal_store(cf1, (vflt4*)(out_can + base + 4));
  __builtin_nontemporal_store(df0, (vflt4*)(out_depth + base));
  __builtin_nontemporal_store(df1, (vflt4*)(out_depth + base + 4));
}

// ---------------------------------------------------------------------------
extern "C" void kernel_launch(void* const* d_in, const int* in_sizes, int n_in,
                              void* d_out, int out_size, void* d_ws, size_t ws_size,
                              hipStream_t stream) {
  // Input order per setup_inputs dict:
  // 0 depth, 1 context, 2 input_feature_map, 3 bin_num, 4 min_depth,
  // 5 max_depth, 6 masks, 7 instances, 8 boxes, 9 labels,
  // 10 W_scale, 11 b_scale, 12 W_shift, 13 b_shift, 14 Wc, 15 bc
  const float* ifm     = (const float*)d_in[2];
  const int*   inst    = (const int*)d_in[7];
  const int*   labels  = (const int*)d_in[9];
  const float* W_scale = (const float*)d_in[10];
  const float* b_scale = (const float*)d_in[11];
  const float* W_shift = (const float*)d_in[12];
  const float* b_shift = (const float*)d_in[13];
  const float* Wc      = (const float*)d_in[14];
  const float* bc      = (const float*)d_in[15];

  float* out       = (float*)d_out;
  float* out_depth = out + OUT_DEPTH;
  float* out_can   = out + OUT_CAN;
  float* out_scale = out + OUT_SCALE;
  float* out_shift = out + OUT_SHIFT;

  float* can_ws  = (float*)d_ws;               // 12800 floats (51.2 KB)
  float* partial = (float*)d_ws + 2 * HW4;     // 200*8448 floats (6.76 MB)

  pool_gemm_kernel<<<NB * NKB, 512, 0, stream>>>(inst, ifm, Wc, bc,
                                                 can_ws, partial);
  finish_kernel<<<BI, 128, 0, stream>>>(partial, labels, W_scale, b_scale,
                                        W_shift, b_shift, out_scale, out_shift);
  out_kernel<<<BI * 50, 256, 0, stream>>>(inst, can_ws, labels, out_scale,
                                          out_shift, out_depth, out_can);
}

// Round 3
// 201.252 us; speedup vs baseline: 1.0275x; 1.0275x over previous
//
#include <hip/hip_runtime.h>

// Problem constants (from reference setup_inputs):
// B=2, I=63, H=W=320, HID=128, C=14, DOWN=4, h4=w4=80
#define NB 2
#define NI 63
#define BI (NB*NI)          // 126
#define HW 320
#define HWF (HW*HW)         // 102400 pixels per (b,i)
#define H4 80
#define HW4 (H4*H4)         // 6400
#define HID 128
#define IFM_B (HID*HW4)     // 819200 floats per batch

#define OUT_DEPTH 0
#define OUT_CAN   (BI*HWF)            // 12902400
#define OUT_SCALE (2*BI*HWF)          // 25804800
#define OUT_SHIFT (2*BI*HWF + BI)     // 25804926

// Pool-GEMM tiling
#define KB 64               // hw4 positions per block
#define NKB (HW4/KB)        // 100 blocks per batch
#define FPAD 68             // fT/mT padded row stride (floats)
#define PROW 132            // partial row stride per i (129 used)
#define PBLK (64*PROW)      // per-block partial floats (8448)

// clang ext vector types for nontemporal builtins (HIP float4/int4 are
// classes -> rejected by __builtin_nontemporal_*)
typedef int   vint4  __attribute__((ext_vector_type(4)));
typedef float vflt4  __attribute__((ext_vector_type(4)));

// ---------------------------------------------------------------------------
// Kernel P: per (b, k-chunk of 64 hw4):
//   - stage fT[c][k] (128x64 ifm tile) and mT[i][k] (64x64 mask tile) in LDS
//   - GEMM: partial[i][c] = sum_k mT[i][k]*fT[c][k]  (register-tiled 4i x 4c)
//   - msum partial per i  -> partial[i][128]
//   - can_small for these 64 hw: sum_c fT[c][j]*Wc[c] + bc -> can_ws
// Reads ifm exactly once across the grid.
// ---------------------------------------------------------------------------
__global__ __launch_bounds__(512) void pool_gemm_kernel(
    const int* __restrict__ inst, const float* __restrict__ ifm,
    const float* __restrict__ Wc, const float* __restrict__ bc,
    float* __restrict__ can_ws, float* __restrict__ partial) {
  __shared__ float fT[128][FPAD];   // 34.8 KB
  __shared__ float mT[64][FPAD];    // 17.4 KB
  __shared__ float wc_s[128];

  int bid = blockIdx.x;             // 0..199
  int b = bid / NKB, kb = bid % NKB;
  int k0 = kb * KB;                 // base hw4 for this chunk
  int t = threadIdx.x;              // 0..511

  if (t < 128) wc_s[t] = Wc[t];

  // ---- stage fT: 128 c x 64 k floats, coalesced float4 global reads ----
  const float* fbase = ifm + (long)b * IFM_B;
#pragma unroll
  for (int s = 0; s < 4; ++s) {
    int v = s * 512 + t;            // 0..2047 float4 slots
    int c = v >> 4;                 // 16 float4 per row
    int jq = v & 15;
    float4 x = *(const float4*)(fbase + c * HW4 + k0 + jq * 4);
    *(float4*)&fT[c][jq * 4] = x;
  }
  // ---- stage mT: 64 i x 64 k (row 63 zero-padded) ----
#pragma unroll
  for (int s = 0; s < 8; ++s) {
    int v = s * 512 + t;            // 0..4095
    int i = v >> 6;
    int j = v & 63;
    int hw4 = k0 + j;
    int r = hw4 / H4, col = hw4 - r * H4;
    float m = 0.f;
    if (i < NI)
      m = (float)__builtin_nontemporal_load(
          inst + ((long)(b * NI + i)) * HWF + r * 4 * HW + col * 4);
    mT[i][j] = m;
  }
  __syncthreads();

  // ---- register-tiled GEMM: thread (ti,tc) -> i in [4ti,4ti+4), c = tc+32v ----
  int ti = t >> 5, tc = t & 31;     // ti 0..15, tc 0..31
  int i0 = ti * 4;
  float acc[4][4];
#pragma unroll
  for (int u = 0; u < 4; ++u)
#pragma unroll
    for (int v = 0; v < 4; ++v) acc[u][v] = 0.f;

  for (int k = 0; k < KB; k += 4) {
    float4 a[4], bb[4];
#pragma unroll
    for (int u = 0; u < 4; ++u) a[u] = *(const float4*)&mT[i0 + u][k];
#pragma unroll
    for (int v = 0; v < 4; ++v) bb[v] = *(const float4*)&fT[tc + 32 * v][k];
#pragma unroll
    for (int u = 0; u < 4; ++u)
#pragma unroll
      for (int v = 0; v < 4; ++v)
        acc[u][v] += a[u].x * bb[v].x + a[u].y * bb[v].y +
                     a[u].z * bb[v].z + a[u].w * bb[v].w;
  }

  // ---- write partials: c = tc + 32v (lanes contiguous in tc -> coalesced) ----
  float* pb = partial + (long)bid * PBLK;
#pragma unroll
  for (int u = 0; u < 4; ++u)
#pragma unroll
    for (int v = 0; v < 4; ++v)
      pb[(i0 + u) * PROW + tc + 32 * v] = acc[u][v];

  // ---- msum partial per i: threads 0..63 sum their mT row ----
  if (t < 64) {
    float ms = 0.f;
#pragma unroll
    for (int q = 0; q < KB / 4; ++q) {
      float4 m4 = *(const float4*)&mT[t][q * 4];
      ms += m4.x + m4.y + m4.z + m4.w;
    }
    pb[t * PROW + 128] = ms;

    // ---- can_small for these 64 hw: column read of fT (2-way bank = free) ----
    float ca = bc[0];
#pragma unroll 8
    for (int c = 0; c < 128; ++c) ca += fT[c][t] * wc_s[c];
    can_ws[b * HW4 + k0 + t] = ca;
  }
}

// ---------------------------------------------------------------------------
// Kernel F: per (b,i): reduce 100 partials -> pooled[c], msum; then
// scale/shift via labels. 126 blocks x 512 threads.
// Latency fix vs prior version: 4 thread-groups each sum 25 chunks with a
// FULLY unrolled loop (25 outstanding loads vs 4) -> ~4-6x fewer serialized
// HBM/L3 latency rounds. msum broadcast via shuffle (no LDS round-trip).
// ---------------------------------------------------------------------------
__global__ __launch_bounds__(512) void finish_kernel(
    const float* __restrict__ partial, const int* __restrict__ labels,
    const float* __restrict__ W_scale, const float* __restrict__ b_scale,
    const float* __restrict__ W_shift, const float* __restrict__ b_shift,
    float* __restrict__ scale_out, float* __restrict__ shift_out) {
  __shared__ float pooled4[4][128];

  int bi = blockIdx.x;            // 0..125
  int b = bi / NI, i = bi % NI;
  int t = threadIdx.x;            // 0..511
  int g = t >> 7;                 // chunk-group 0..3
  int c = t & 127;                // channel

  const float* pb = partial + ((long)b * NKB) * PBLK + i * PROW;

  float acc = 0.f;
#pragma unroll
  for (int q = 0; q < 25; ++q)
    acc += __builtin_nontemporal_load(&pb[(long)(g * 25 + q) * PBLK + c]);
  pooled4[g][c] = acc;
  __syncthreads();

  if (t < 64) {
    // msum: lanes 0..63 each grab two chunks' msum slots, shuffle-reduce
    float ms = pb[(long)t * PBLK + 128];
    if (t + 64 < NKB) ms += pb[(long)(t + 64) * PBLK + 128];
    for (int off = 32; off; off >>= 1) ms += __shfl_down(ms, off, 64);
    ms = __shfl(ms, 0, 64);       // broadcast total to all lanes

    int lab = labels[bi];
    float valid = (lab != 0) ? 1.f : 0.f;
    float inv = 1.f / fmaxf(ms, 1.f);
    float p0 = pooled4[0][t] + pooled4[1][t] + pooled4[2][t] + pooled4[3][t];
    float p1 = pooled4[0][t + 64] + pooled4[1][t + 64] +
               pooled4[2][t + 64] + pooled4[3][t + 64];
    const float* ws = W_scale + lab * HID;
    const float* wh = W_shift + lab * HID;
    float sa = p0 * ws[t] + p1 * ws[t + 64];
    float sh = p0 * wh[t] + p1 * wh[t + 64];
    for (int off = 32; off; off >>= 1) {
      sa += __shfl_down(sa, off, 64);
      sh += __shfl_down(sh, off, 64);
    }
    if (t == 0) {
      scale_out[bi] = (sa * inv + b_scale[lab]) * valid;
      shift_out[bi] = (sh * inv + b_shift[lab]) * valid;
    }
  }
}

// ---------------------------------------------------------------------------
// Kernel C: full-res outputs. 2048 contiguous pixels per block (50 blocks per
// (b,i) image). Each thread: 2x int4 NT loads, 4x float4 NT stores (8 px).
// ---------------------------------------------------------------------------
__global__ __launch_bounds__(256) void out_kernel(
    const int* __restrict__ inst, const float* __restrict__ can_ws,
    const int* __restrict__ labels,
    const float* __restrict__ scale_arr, const float* __restrict__ shift_arr,
    float* __restrict__ out_depth, float* __restrict__ out_can) {
  int blk = blockIdx.x;          // 0..6299
  int bi = blk / 50;
  int chunk = blk - bi * 50;
  int b = bi / NI;
  int pix = chunk * 2048 + threadIdx.x * 8;
  int h = pix / HW, w = pix - h * HW;   // all 8 pixels in same row (320%8==0)

  // w is a multiple of 8 -> (w>>2) even -> float2-aligned; covers both w4 cells
  const float2 c2 = *(const float2*)(can_ws + b * HW4 + (h >> 2) * H4 + (w >> 2));
  int lab = labels[bi];
  float valid = (lab != 0) ? 1.f : 0.f;
  float sc = scale_arr[bi];
  float sh = shift_arr[bi];
  float cv0 = c2.x * valid;
  float cv1 = c2.y * valid;

  long base = (long)bi * HWF + pix;
  const vint4 iv0 = __builtin_nontemporal_load((const vint4*)(inst + base));
  const vint4 iv1 = __builtin_nontemporal_load((const vint4*)(inst + base + 4));
  vflt4 cf0, cf1, df0, df1;
  cf0.x = cv0 * (float)iv0.x;
  cf0.y = cv0 * (float)iv0.y;
  cf0.z = cv0 * (float)iv0.z;
  cf0.w = cv0 * (float)iv0.w;
  cf1.x = cv1 * (float)iv1.x;
  cf1.y = cv1 * (float)iv1.y;
  cf1.z = cv1 * (float)iv1.z;
  cf1.w = cv1 * (float)iv1.w;
  df0.x = fmaxf(cf0.x * sc + sh, 0.001f);
  df0.y = fmaxf(cf0.y * sc + sh, 0.001f);
  df0.z = fmaxf(cf0.z * sc + sh, 0.001f);
  df0.w = fmaxf(cf0.w * sc + sh, 0.001f);
  df1.x = fmaxf(cf1.x * sc + sh, 0.001f);
  df1.y = fmaxf(cf1.y * sc + sh, 0.001f);
  df1.z = fmaxf(cf1.z * sc + sh, 0.001f);
  df1.w = fmaxf(cf1.w * sc + sh, 0.001f);
  __builtin_nontemporal_store(cf0, (vflt4*)(out_can + base));
  __builtin_nontemporal_store(cf1, (vflt4*)(out_can + base + 4));
  __builtin_nontemporal_store(df0, (vflt4*)(out_depth + base));
  __builtin_nontemporal_store(df1, (vflt4*)(out_depth + base + 4));
}

// ---------------------------------------------------------------------------
extern "C" void kernel_launch(void* const* d_in, const int* in_sizes, int n_in,
                              void* d_out, int out_size, void* d_ws, size_t ws_size,
                              hipStream_t stream) {
  // Input order per setup_inputs dict:
  // 0 depth, 1 context, 2 input_feature_map, 3 bin_num, 4 min_depth,
  // 5 max_depth, 6 masks, 7 instances, 8 boxes, 9 labels,
  // 10 W_scale, 11 b_scale, 12 W_shift, 13 b_shift, 14 Wc, 15 bc
  const float* ifm     = (const float*)d_in[2];
  const int*   inst    = (const int*)d_in[7];
  const int*   labels  = (const int*)d_in[9];
  const float* W_scale = (const float*)d_in[10];
  const float* b_scale = (const float*)d_in[11];
  const float* W_shift = (const float*)d_in[12];
  const float* b_shift = (const float*)d_in[13];
  const float* Wc      = (const float*)d_in[14];
  const float* bc      = (const float*)d_in[15];

  float* out       = (float*)d_out;
  float* out_depth = out + OUT_DEPTH;
  float* out_can   = out + OUT_CAN;
  float* out_scale = out + OUT_SCALE;
  float* out_shift = out + OUT_SHIFT;

  float* can_ws  = (float*)d_ws;               // 12800 floats (51.2 KB)
  float* partial = (float*)d_ws + 2 * HW4;     // 200*8448 floats (6.76 MB)

  pool_gemm_kernel<<<NB * NKB, 512, 0, stream>>>(inst, ifm, Wc, bc,
                                                 can_ws, partial);
  finish_kernel<<<BI, 512, 0, stream>>>(partial, labels, W_scale, b_scale,
                                        W_shift, b_shift, out_scale, out_shift);
  out_kernel<<<BI * 50, 256, 0, stream>>>(inst, can_ws, labels, out_scale,
                                          out_shift, out_depth, out_can);
}